// Round 6
// baseline (98.752 us; speedup 1.0000x reference)
//
#include <hip/hip_runtime.h>

typedef __attribute__((ext_vector_type(8))) short short8;
typedef __attribute__((ext_vector_type(4))) short short4v;
typedef __attribute__((ext_vector_type(4))) float f32x4;

#define VM(n) asm volatile("s_waitcnt vmcnt(" #n ")" ::: "memory")
#define LGKM0 asm volatile("s_waitcnt lgkmcnt(0)" ::: "memory")

namespace {

constexpr int DIN  = 768;
constexpr int HID  = 64;
constexpr int NEXP = 6;
constexpr int CDIM  = 320;
constexpr int NZ    = 64;
constexpr int NTOK  = 20480;

constexpr long long XP_OFF   = 0;
constexpr long long ZP_OFF   = 12582912LL;
constexpr long long LOSS_OFF = 15728640LL;
constexpr long long LG_OFF   = 15728641LL;

__device__ inline unsigned short f2bf(float f) {
  union { float f; unsigned u; } v{f};
  return (unsigned short)((v.u + 0x7FFFu + ((v.u >> 16) & 1u)) >> 16);  // RNE
}
__device__ inline float b2f(unsigned short s) {
  union { unsigned u; float f; } v{(unsigned)s << 16};
  return v.f;
}
__device__ inline void gload16(const void* g, void* l) {
  __builtin_amdgcn_global_load_lds(
      (const __attribute__((address_space(1))) unsigned*)g,
      (__attribute__((address_space(3))) unsigned*)l, 16, 0, 0);
}
__device__ inline int row_base(int n) {
  int bb = n / CDIM, c = n - bb * CDIM;
  return (c < NZ) ? (int)(ZP_OFF + (long long)(bb * NZ + c) * DIN)
                  : (int)(XP_OFF + (long long)(bb * (CDIM - NZ) + (c - NZ)) * DIN);
}

// ---------------- K0: weight prep (512 threads) ----------------
// b<72:  ewb_t[e][h][k] = bf16(expert_w[e][k][h])
// b<84:  fwb = bf16(ffn1_w)
// b==84: wgT[e][d] = fp32 w_gate[d][e]
__global__ __launch_bounds__(512) void prep_kernel(
    const float* __restrict__ ew, const float* __restrict__ fw,
    const float* __restrict__ wg,
    unsigned short* __restrict__ ewb_t, unsigned short* __restrict__ fwb,
    float* __restrict__ wgT)
{
  int b = blockIdx.x, tid = threadIdx.x;
  __shared__ float t_lds[64][65];
  if (b < 72) {
    int e = b / 12, kc = (b % 12) * 64;
    const float* src = ew + (size_t)e * DIN * HID + (size_t)kc * HID;
    #pragma unroll
    for (int it = 0; it < 8; ++it) {
      int f = it * 512 + tid; int ky = f >> 6, h = f & 63;
      t_lds[h][ky] = src[ky * 64 + h];
    }
    __syncthreads();
    unsigned short* dst = ewb_t + (size_t)e * DIN * HID + kc;
    #pragma unroll
    for (int it = 0; it < 8; ++it) {
      int f = it * 512 + tid; int h = f >> 6, ky = f & 63;
      dst[(size_t)h * DIN + ky] = f2bf(t_lds[h][ky]);
    }
  } else if (b < 84) {
    int base = (b - 72) * 4096;
    #pragma unroll
    for (int it = 0; it < 8; ++it) {
      int idx = base + it * 512 + tid;
      fwb[idx] = f2bf(fw[idx]);
    }
  } else {
    for (int idx = tid; idx < NEXP * DIN; idx += 512) {
      int e = idx / DIN, d = idx - e * DIN;
      wgT[e * DIN + d] = wg[d * NEXP + e];
    }
  }
}

// ---------------- K1: fused gate + dense-expert GEMM + combine + FFN ----------
// 320 blocks x 512 threads (8 waves 2x4); 64 tokens/block; BK=32, 24 phases.
// A reg-staged from fp32 x/xi (gate logits accumulate from same regs);
// B via global_load_lds, counted vmcnt (never 0 mid-loop), 2 raw barriers/phase.
// LDS: A dbuf [0,8192) | B dbuf [8192,57344) | epi: y[0,8192), h[8192,58368),
//      fwb HI [58368,74752) / LO [8192,24576).
__global__ __launch_bounds__(512) void moe_kernel(
    const float* __restrict__ x, const float* __restrict__ xi,
    const float* __restrict__ wgT,
    const unsigned short* __restrict__ ewb_t, const float* __restrict__ eb,
    const unsigned short* __restrict__ fwb, const float* __restrict__ fb,
    float* __restrict__ out, float4* __restrict__ rec_g)
{
  __shared__ __align__(16) char smem[74752];
  __shared__ float4 rec_lds[64];
  __shared__ int rb[64];

  int tid = threadIdx.x, lane = tid & 63, wid = tid >> 6;
  int qw = lane >> 4, l15 = lane & 15;
  int wm = wid >> 2, wn = wid & 3;
  int t0 = blockIdx.x * 64;

  if (tid < 64) rb[tid] = row_base(t0 + tid);

  // B staging (verified round-4 pattern)
  size_t b_src[3]; int b_dst[3];
  #pragma unroll
  for (int it = 0; it < 3; ++it) {
    int F = it * 512 + tid, r = F >> 2, s = F & 3;
    b_src[it] = (size_t)r * DIN + ((s ^ (r & 3) ^ ((r & 4) >> 1)) << 3);
    b_dst[it] = (it * 512 + wid * 64) * 16;
  }
  // A production: thread (ra = token row, sa = 4-dim group within 32-chunk)
  int ra = tid >> 3, sa = tid & 7;
  const float* xrow  = x  + (size_t)(t0 + ra) * DIN + sa * 4;
  const float* xirow = xi + (size_t)(t0 + ra) * DIN + sa * 4;
  int awz = ra * 64 + ((((sa >> 1) ^ (ra & 3) ^ ((ra & 4) >> 1))) << 4) + (sa & 1) * 8;

  f32x4 acc[2][6];
  #pragma unroll
  for (int m = 0; m < 2; ++m)
    #pragma unroll
    for (int n = 0; n < 6; ++n) acc[m][n] = (f32x4){0.f, 0.f, 0.f, 0.f};

  int aoff[2], boff[6];
  #pragma unroll
  for (int m = 0; m < 2; ++m) {
    int row = wm * 32 + m * 16 + l15;
    aoff[m] = row * 64 + ((qw ^ (row & 3) ^ ((row & 4) >> 1)) << 4);
  }
  #pragma unroll
  for (int n = 0; n < 6; ++n) {
    int row = wn * 96 + n * 16 + l15;
    boff[n] = row * 64 + ((qw ^ (row & 3) ^ ((row & 4) >> 1)) << 4);
  }

  float lg[NEXP];
  #pragma unroll
  for (int e = 0; e < NEXP; ++e) lg[e] = 0.f;

  // ---- prologue: chunk 0 (B gloads first for head start) ----
  #pragma unroll
  for (int it = 0; it < 3; ++it)
    gload16(ewb_t + b_src[it], smem + 8192 + b_dst[it]);
  {
    float4 a0 = *(const float4*)xrow;
    float4 i0 = *(const float4*)xirow;
    float tv0 = a0.x + i0.x, tv1 = a0.y + i0.y, tv2 = a0.z + i0.z, tv3 = a0.w + i0.w;
    #pragma unroll
    for (int e = 0; e < NEXP; ++e) {
      float4 w = *(const float4*)(wgT + e * DIN + sa * 4);
      lg[e] += tv0 * w.x + tv1 * w.y + tv2 * w.z + tv3 * w.w;
    }
    short4v av;
    av[0] = (short)f2bf(tv0); av[1] = (short)f2bf(tv1);
    av[2] = (short)f2bf(tv2); av[3] = (short)f2bf(tv3);
    *(short4v*)(smem + awz) = av;
  }
  LGKM0;

  // ---- K-loop: 24 phases ----
  for (int k = 0; k < 24; ++k) {
    const char* cA = smem + (k & 1) * 4096;
    const char* cB = smem + 8192 + (k & 1) * 24576;
    char* nA = (char*)smem + ((k + 1) & 1) * 4096;
    char* nB = (char*)smem + 8192 + ((k + 1) & 1) * 24576;
    float4 ax2, ix2;
    if (k < 23) {
      ax2 = *(const float4*)(xrow + (k + 1) * 32);
      ix2 = *(const float4*)(xirow + (k + 1) * 32);
      #pragma unroll
      for (int it = 0; it < 3; ++it)
        gload16(ewb_t + b_src[it] + (size_t)(k + 1) * 32, nB + b_dst[it]);
      VM(5);      // drain prior phase only; 3 nB + 2 reg loads stay in flight
    } else {
      VM(0);
    }
    __builtin_amdgcn_s_barrier();
    __builtin_amdgcn_sched_barrier(0);
    short8 af[2], bfv[6];
    #pragma unroll
    for (int m = 0; m < 2; ++m) af[m] = *(const short8*)(cA + aoff[m]);
    #pragma unroll
    for (int n = 0; n < 6; ++n) bfv[n] = *(const short8*)(cB + boff[n]);
    __builtin_amdgcn_s_setprio(1);
    #pragma unroll
    for (int m = 0; m < 2; ++m)
      #pragma unroll
      for (int n = 0; n < 6; ++n)
        acc[m][n] = __builtin_amdgcn_mfma_f32_16x16x32_bf16(af[m], bfv[n], acc[m][n], 0, 0, 0);
    __builtin_amdgcn_s_setprio(0);
    __builtin_amdgcn_sched_barrier(0);
    if (k < 23) {
      int d0 = (k + 1) * 32 + sa * 4;
      float tv0 = ax2.x + ix2.x, tv1 = ax2.y + ix2.y,
            tv2 = ax2.z + ix2.z, tv3 = ax2.w + ix2.w;
      #pragma unroll
      for (int e = 0; e < NEXP; ++e) {
        float4 w = *(const float4*)(wgT + e * DIN + d0);   // L1-resident table
        lg[e] += tv0 * w.x + tv1 * w.y + tv2 * w.z + tv3 * w.w;
      }
      short4v av;
      av[0] = (short)f2bf(tv0); av[1] = (short)f2bf(tv1);
      av[2] = (short)f2bf(tv2); av[3] = (short)f2bf(tv3);
      *(short4v*)(nA + awz) = av;
    }
    LGKM0;
    __builtin_amdgcn_s_barrier();
  }

  // issue fwb chunk 0 into HI buffer (in flight during finalize/combine)
  #pragma unroll
  for (int it = 0; it < 2; ++it) {
    int F = it * 512 + tid, r = F >> 3, s = F & 7;
    gload16(fwb + (size_t)r * HID + ((s ^ (r & 7)) << 3),
            smem + 58368 + (it * 512 + wid * 64) * 16);
  }

  // ---- gate finalize: reduce over 8 sa-lanes per token ----
  #pragma unroll
  for (int e = 0; e < NEXP; ++e) {
    float v = lg[e];
    v += __shfl_xor(v, 1, 64);
    v += __shfl_xor(v, 2, 64);
    v += __shfl_xor(v, 4, 64);
    lg[e] = v;
  }
  if (sa == 0) {
    int e0 = 0; float v0 = lg[0];
    #pragma unroll
    for (int j = 1; j < NEXP; ++j) if (lg[j] > v0) { v0 = lg[j]; e0 = j; }
    int e1 = 0; float v1 = -3.4e38f;
    #pragma unroll
    for (int j = 0; j < NEXP; ++j) if (j != e0 && lg[j] > v1) { v1 = lg[j]; e1 = j; }
    float g0 = 1.f / (1.f + expf(v1 - v0));
    #pragma unroll
    for (int e = 0; e < NEXP; ++e)
      out[LG_OFF + (size_t)(t0 + ra) * NEXP + e] = lg[e];
    float4 r4 = make_float4((float)e0, (float)e1, g0, 1.f - g0);
    rec_lds[ra] = r4;
    rec_g[t0 + ra] = r4;
  }

  // ---- h -> LDS bf16 [64][392] ----
  unsigned short* hl = (unsigned short*)(smem + 8192);
  #pragma unroll
  for (int m = 0; m < 2; ++m)
    #pragma unroll
    for (int n = 0; n < 6; ++n)
      #pragma unroll
      for (int i = 0; i < 4; ++i) {
        int row = wm * 32 + m * 16 + qw * 4 + i;
        int col = wn * 96 + n * 16 + l15;
        hl[row * 392 + col] = f2bf(acc[m][n][i]);
      }
  LGKM0;
  __builtin_amdgcn_s_barrier();

  // ---- gated combine -> y bf16 (swizzled) at smem[0,8192) ----
  {
    int t = tid >> 3, j0 = (tid & 7) * 8;
    float4 rr = rec_lds[t];
    int e0 = (int)rr.x, e1 = (int)rr.y;
    float g0 = rr.z, g1 = rr.w;
    short8 h0 = *(const short8*)(hl + t * 392 + e0 * 64 + j0);
    short8 h1 = *(const short8*)(hl + t * 392 + e1 * 64 + j0);
    const float4* ep0 = (const float4*)(eb + e0 * 64 + j0);
    const float4* ep1 = (const float4*)(eb + e1 * 64 + j0);
    float4 b0a = ep0[0], b0b = ep0[1], b1a = ep1[0], b1b = ep1[1];
    float be0[8] = {b0a.x, b0a.y, b0a.z, b0a.w, b0b.x, b0b.y, b0b.z, b0b.w};
    float be1[8] = {b1a.x, b1a.y, b1a.z, b1a.w, b1b.x, b1b.y, b1b.z, b1b.w};
    short8 ov;
    #pragma unroll
    for (int j = 0; j < 8; ++j) {
      float v = g0 * (b2f((unsigned short)h0[j]) + be0[j])
              + g1 * (b2f((unsigned short)h1[j]) + be1[j]);
      ov[j] = (short)f2bf(v);
    }
    *(short8*)(smem + t * 128 + ((((tid & 7)) ^ (t & 7)) << 4)) = ov;
  }
  LGKM0;
  __builtin_amdgcn_s_barrier();

  // ---- FFN: 6 chunks of 128 cols, fwb dbuf HI/LO, counted vmcnt ----
  for (int c = 0; c < 6; ++c) {
    const char* cF = smem + ((c & 1) ? 8192 : 58368);
    char* nF = (char*)smem + ((c & 1) ? 58368 : 8192);
    if (c < 5) {
      #pragma unroll
      for (int it = 0; it < 2; ++it) {
        int F = it * 512 + tid, r = F >> 3, s = F & 7;
        gload16(fwb + (size_t)((c + 1) * 128 + r) * HID + ((s ^ (r & 7)) << 3),
                nF + (it * 512 + wid * 64) * 16);
      }
      VM(2);
    } else {
      VM(0);
    }
    __builtin_amdgcn_s_barrier();
    __builtin_amdgcn_sched_barrier(0);
    f32x4 a2[2][2];
    #pragma unroll
    for (int m = 0; m < 2; ++m)
      #pragma unroll
      for (int n = 0; n < 2; ++n) a2[m][n] = (f32x4){0.f, 0.f, 0.f, 0.f};
    #pragma unroll
    for (int kk = 0; kk < 2; ++kk) {
      short8 ay[2], bw[2];
      #pragma unroll
      for (int m = 0; m < 2; ++m) {
        int row = wm * 32 + m * 16 + l15;
        ay[m] = *(const short8*)(smem + row * 128 + (((kk * 4 + qw) ^ (row & 7)) << 4));
      }
      #pragma unroll
      for (int n = 0; n < 2; ++n) {
        int rw = wn * 32 + n * 16 + l15;
        bw[n] = *(const short8*)(cF + rw * 128 + (((kk * 4 + qw) ^ (rw & 7)) << 4));
      }
      __builtin_amdgcn_s_setprio(1);
      #pragma unroll
      for (int m = 0; m < 2; ++m)
        #pragma unroll
        for (int n = 0; n < 2; ++n)
          a2[m][n] = __builtin_amdgcn_mfma_f32_16x16x32_bf16(ay[m], bw[n], a2[m][n], 0, 0, 0);
      __builtin_amdgcn_s_setprio(0);
    }
    #pragma unroll
    for (int n = 0; n < 2; ++n) {
      int col = c * 128 + wn * 32 + n * 16 + l15;
      float bias = fb[col];
      #pragma unroll
      for (int m = 0; m < 2; ++m)
        #pragma unroll
        for (int i = 0; i < 4; ++i) {
          int rl = wm * 32 + m * 16 + qw * 4 + i;
          out[(size_t)rb[rl] + col] = a2[m][n][i] + bias;
        }
    }
    __builtin_amdgcn_sched_barrier(0);
    __builtin_amdgcn_s_barrier();
  }
}

// ---------------- K2: load-balance loss ----------------
__global__ __launch_bounds__(256) void loss_kernel(
    const float4* __restrict__ rec, float* __restrict__ out)
{
  float imp[NEXP], ld[NEXP];
  #pragma unroll
  for (int e = 0; e < NEXP; ++e) { imp[e] = 0.f; ld[e] = 0.f; }
  for (int n = threadIdx.x; n < NTOK; n += 256) {
    float4 r = rec[n];
    int e0 = (int)r.x, e1 = (int)r.y;
    #pragma unroll
    for (int e = 0; e < NEXP; ++e) {
      imp[e] += (e == e0 ? r.z : 0.f) + (e == e1 ? r.w : 0.f);
      ld[e]  += (e == e0 ? 1.f : 0.f) + (e == e1 ? 1.f : 0.f);
    }
  }
  #pragma unroll
  for (int e = 0; e < NEXP; ++e) {
    float a = imp[e], b = ld[e];
    #pragma unroll
    for (int off = 32; off >= 1; off >>= 1) {
      a += __shfl_xor(a, off, 64);
      b += __shfl_xor(b, off, 64);
    }
    imp[e] = a; ld[e] = b;
  }
  __shared__ float simp[4][NEXP], sld[4][NEXP];
  int wid = threadIdx.x >> 6, lane = threadIdx.x & 63;
  if (lane == 0) {
    #pragma unroll
    for (int e = 0; e < NEXP; ++e) { simp[wid][e] = imp[e]; sld[wid][e] = ld[e]; }
  }
  __syncthreads();
  if (threadIdx.x == 0) {
    float It[NEXP], Lt[NEXP], mi = 0.f, ml = 0.f;
    #pragma unroll
    for (int e = 0; e < NEXP; ++e) {
      It[e] = simp[0][e] + simp[1][e] + simp[2][e] + simp[3][e];
      Lt[e] = sld[0][e] + sld[1][e] + sld[2][e] + sld[3][e];
      mi += It[e]; ml += Lt[e];
    }
    mi /= NEXP; ml /= NEXP;
    float vi = 0.f, vl = 0.f;
    #pragma unroll
    for (int e = 0; e < NEXP; ++e) {
      vi += (It[e] - mi) * (It[e] - mi);
      vl += (Lt[e] - ml) * (Lt[e] - ml);
    }
    vi /= NEXP; vl /= NEXP;
    out[LOSS_OFF] = vi / (mi * mi + 1e-10f) + vl / (ml * ml + 1e-10f);
  }
}

}  // namespace

extern "C" void kernel_launch(void* const* d_in, const int* in_sizes, int n_in,
                              void* d_out, int out_size, void* d_ws, size_t ws_size,
                              hipStream_t stream)
{
  const float* x  = (const float*)d_in[0];
  const float* xi = (const float*)d_in[1];
  const float* wg = (const float*)d_in[2];
  const float* ew = (const float*)d_in[3];
  const float* eb = (const float*)d_in[4];
  const float* fw = (const float*)d_in[5];
  const float* fb = (const float*)d_in[6];
  float* out = (float*)d_out;

  char* w = (char*)d_ws;
  float4*         rec   = (float4*)w;                              // 327,680 B
  unsigned short* ewb_t = (unsigned short*)(w + 327680);           // 589,824 B
  unsigned short* fwb   = (unsigned short*)(w + 327680 + 589824);  //  98,304 B
  float*          wgT   = (float*)(w + 327680 + 589824 + 98304);   //  18,432 B

  prep_kernel<<<85, 512, 0, stream>>>(ew, fw, wg, ewb_t, fwb, wgT);
  moe_kernel<<<320, 512, 0, stream>>>(x, xi, wgT, ewb_t, eb, fwb, fb, out, rec);
  loss_kernel<<<1, 256, 0, stream>>>(rec, out);
}

// Round 7
// 68.377 us; speedup vs baseline: 1.4442x; 1.4442x over previous
//
#include <hip/hip_runtime.h>

typedef __attribute__((ext_vector_type(8))) short short8;
typedef __attribute__((ext_vector_type(4))) short short4v;
typedef __attribute__((ext_vector_type(4))) float f32x4;

#define VM(n) asm volatile("s_waitcnt vmcnt(" #n ")" ::: "memory")
#define LGKM0 asm volatile("s_waitcnt lgkmcnt(0)" ::: "memory")

namespace {

constexpr int DIN  = 768;
constexpr int HID  = 64;
constexpr int NEXP = 6;
constexpr int CDIM  = 320;
constexpr int NZ    = 64;
constexpr int NTOK  = 20480;

constexpr long long XP_OFF   = 0;
constexpr long long ZP_OFF   = 12582912LL;
constexpr long long LOSS_OFF = 15728640LL;
constexpr long long LG_OFF   = 15728641LL;

__device__ inline unsigned short f2bf(float f) {
  union { float f; unsigned u; } v{f};
  return (unsigned short)((v.u + 0x7FFFu + ((v.u >> 16) & 1u)) >> 16);  // RNE
}
__device__ inline float b2f(unsigned short s) {
  union { unsigned u; float f; } v{(unsigned)s << 16};
  return v.f;
}
__device__ inline void gload16(const void* g, void* l) {
  __builtin_amdgcn_global_load_lds(
      (const __attribute__((address_space(1))) unsigned*)g,
      (__attribute__((address_space(3))) unsigned*)l, 16, 0, 0);
}
// float-offset of token n's output row (also where its bf16 tok staging lives)
__device__ inline int row_base(int n) {
  int bb = n / CDIM, c = n - bb * CDIM;
  return (c < NZ) ? (int)(ZP_OFF + (long long)(bb * NZ + c) * DIN)
                  : (int)(XP_OFF + (long long)(bb * (CDIM - NZ) + (c - NZ)) * DIN);
}

// ---------------- K0: weight prep + gate + tok staging ----------------
// blocks 0-71:  ewb_t[e][h][k] = bf16(expert_w[e][k][h])
// blocks 72-83: fwb = bf16(ffn1_w)
// blocks 84+ :  gate, 8 tokens/block (4 waves x 2), wg LDS-resident
//               transposed -> conflict-free contiguous ds_read_b128.
__global__ __launch_bounds__(256) void pre_kernel(
    const float* __restrict__ x, const float* __restrict__ xi,
    const float* __restrict__ wg, const float* __restrict__ ew,
    const float* __restrict__ fw,
    float* __restrict__ out, float4* __restrict__ rec,
    unsigned short* __restrict__ ewb_t, unsigned short* __restrict__ fwb)
{
  int b = blockIdx.x, tid = threadIdx.x;
  __shared__ __align__(16) char sbuf[18432];   // t_lds (16.6KB) or wgl (18KB)
  if (b < 72) {
    float (*t_lds)[65] = (float(*)[65])sbuf;
    int e = b / 12, kc = (b % 12) * 64;
    const float* src = ew + (size_t)e * DIN * HID + (size_t)kc * HID;
    #pragma unroll
    for (int it = 0; it < 16; ++it) {
      int f = it * 256 + tid; int ky = f >> 6, h = f & 63;
      t_lds[h][ky] = src[ky * 64 + h];
    }
    __syncthreads();
    unsigned short* dst = ewb_t + (size_t)e * DIN * HID + kc;
    #pragma unroll
    for (int it = 0; it < 16; ++it) {
      int f = it * 256 + tid; int h = f >> 6, ky = f & 63;
      dst[(size_t)h * DIN + ky] = f2bf(t_lds[h][ky]);
    }
    return;
  }
  if (b < 84) {
    int base = (b - 72) * 4096;
    #pragma unroll
    for (int it = 0; it < 16; ++it) {
      int idx = base + it * 256 + tid;
      fwb[idx] = f2bf(fw[idx]);
    }
    return;
  }
  // ---- gate + tok: wgT staged in LDS [6][768] (transposed) ----
  float (*wgl)[DIN] = (float(*)[DIN])sbuf;
  for (int idx = tid; idx < NEXP * DIN; idx += 256) {
    int d = idx / NEXP, e = idx - d * NEXP;
    wgl[e][d] = wg[idx];       // coalesced read; one-time scattered write
  }
  __syncthreads();

  int wid = tid >> 6, lane = tid & 63;
  int gb = b - 84;
  #pragma unroll
  for (int t = 0; t < 2; ++t) {
    int n = gb * 8 + t * 4 + wid;
    const float4* xv  = reinterpret_cast<const float4*>(x  + (size_t)n * DIN);
    const float4* xiv = reinterpret_cast<const float4*>(xi + (size_t)n * DIN);
    unsigned short* tk = (unsigned short*)out + (size_t)row_base(n) * 2;

    float lg[NEXP];
    #pragma unroll
    for (int e = 0; e < NEXP; ++e) lg[e] = 0.f;

    #pragma unroll
    for (int j = 0; j < 3; ++j) {
      int f = lane + 64 * j;
      float4 a = xv[f], bq = xiv[f];
      float t0 = a.x + bq.x, t1 = a.y + bq.y, t2 = a.z + bq.z, t3 = a.w + bq.w;
      short4v tv;
      tv[0] = (short)f2bf(t0); tv[1] = (short)f2bf(t1);
      tv[2] = (short)f2bf(t2); tv[3] = (short)f2bf(t3);
      *(short4v*)(tk + f * 4) = tv;
      #pragma unroll
      for (int e = 0; e < NEXP; ++e) {
        float4 w = *(const float4*)(&wgl[e][f * 4]);   // 16B/lane contiguous: conflict-free
        lg[e] += t0 * w.x + t1 * w.y + t2 * w.z + t3 * w.w;
      }
    }
    #pragma unroll
    for (int e = 0; e < NEXP; ++e) {
      float v = lg[e];
      #pragma unroll
      for (int off = 32; off >= 1; off >>= 1) v += __shfl_xor(v, off, 64);
      lg[e] = v;
    }
    int e0 = 0; float v0 = lg[0];
    #pragma unroll
    for (int j = 1; j < NEXP; ++j) if (lg[j] > v0) { v0 = lg[j]; e0 = j; }
    int e1 = 0; float v1 = -3.4e38f;
    #pragma unroll
    for (int j = 0; j < NEXP; ++j) if (j != e0 && lg[j] > v1) { v1 = lg[j]; e1 = j; }
    float g0 = 1.f / (1.f + expf(v1 - v0));
    if (lane < NEXP) {
      float myv = lg[0];
      #pragma unroll
      for (int e = 1; e < NEXP; ++e) if (lane == e) myv = lg[e];
      out[LG_OFF + (size_t)n * NEXP + lane] = myv;
    }
    if (lane == 0) rec[n] = make_float4((float)e0, (float)e1, g0, 1.f - g0);
  }
}

// ---------------- K1: GEMM (all experts) + combine + FFN, counted-vmcnt ----
// M=64 tok/block, N=384, BK=32, 24 phases, 512 threads (8 waves 2x4).
// Block 320 computes the load-balance loss.  (round-4 verified, verbatim)
__global__ __launch_bounds__(512) void moe_kernel(
    const unsigned short* __restrict__ ewb_t, const float* __restrict__ eb,
    const unsigned short* __restrict__ fwb, const float* __restrict__ fb,
    const float4* __restrict__ rec, float* __restrict__ out)
{
  __shared__ __align__(16) char smem[74752];
  __shared__ int rb[64];
  __shared__ float simp[8][NEXP], sld[8][NEXP];

  int tid = threadIdx.x, lane = tid & 63, wid = tid >> 6;
  int qw = lane >> 4, l15 = lane & 15;
  int wm = wid >> 2, wn = wid & 3;

  if (blockIdx.x == 320) {   // ---- loss ----
    float imp[NEXP], ld[NEXP];
    #pragma unroll
    for (int e = 0; e < NEXP; ++e) { imp[e] = 0.f; ld[e] = 0.f; }
    for (int n = tid; n < NTOK; n += 512) {
      float4 r = rec[n];
      int e0 = (int)r.x, e1 = (int)r.y;
      #pragma unroll
      for (int e = 0; e < NEXP; ++e) {
        imp[e] += (e == e0 ? r.z : 0.f) + (e == e1 ? r.w : 0.f);
        ld[e]  += (e == e0 ? 1.f : 0.f) + (e == e1 ? 1.f : 0.f);
      }
    }
    #pragma unroll
    for (int e = 0; e < NEXP; ++e) {
      float a = imp[e], bq = ld[e];
      #pragma unroll
      for (int off = 32; off >= 1; off >>= 1) {
        a += __shfl_xor(a, off, 64);
        bq += __shfl_xor(bq, off, 64);
      }
      imp[e] = a; ld[e] = bq;
    }
    if (lane == 0) {
      #pragma unroll
      for (int e = 0; e < NEXP; ++e) { simp[wid][e] = imp[e]; sld[wid][e] = ld[e]; }
    }
    __syncthreads();
    if (tid == 0) {
      float It[NEXP], Lt[NEXP], mi = 0.f, ml = 0.f;
      #pragma unroll
      for (int e = 0; e < NEXP; ++e) {
        It[e] = 0.f; Lt[e] = 0.f;
        #pragma unroll
        for (int w = 0; w < 8; ++w) { It[e] += simp[w][e]; Lt[e] += sld[w][e]; }
        mi += It[e]; ml += Lt[e];
      }
      mi /= NEXP; ml /= NEXP;
      float vi = 0.f, vl = 0.f;
      #pragma unroll
      for (int e = 0; e < NEXP; ++e) {
        vi += (It[e] - mi) * (It[e] - mi);
        vl += (Lt[e] - ml) * (Lt[e] - ml);
      }
      vi /= NEXP; vl /= NEXP;
      out[LOSS_OFF] = vi / (mi * mi + 1e-10f) + vl / (ml * ml + 1e-10f);
    }
    return;
  }

  int t0 = blockIdx.x * 64;
  const unsigned short* tokb = (const unsigned short*)out;

  // per-thread staging sources
  size_t b_src[3]; int b_dst[3];
  #pragma unroll
  for (int it = 0; it < 3; ++it) {
    int F = it * 512 + tid, r = F >> 2, s = F & 3;
    b_src[it] = (size_t)r * DIN + ((s ^ (r & 3) ^ ((r & 4) >> 1)) << 3);
    b_dst[it] = (it * 512 + wid * 64) * 16;
  }
  int ar = tid >> 2, as = tid & 3;
  size_t a_src = (size_t)row_base(t0 + ar) * 2 +
                 ((as ^ (ar & 3) ^ ((ar & 4) >> 1)) << 3);
  int a_dst = (wid * 64) * 16;

  if (tid < 64) rb[tid] = row_base(t0 + tid);

  // prologue: chunk 0
  #pragma unroll
  for (int it = 0; it < 3; ++it)
    gload16(ewb_t + b_src[it], smem + 8192 + b_dst[it]);
  if (tid < 256) gload16(tokb + a_src, smem + a_dst);

  f32x4 acc[2][6];
  #pragma unroll
  for (int m = 0; m < 2; ++m)
    #pragma unroll
    for (int n = 0; n < 6; ++n) acc[m][n] = (f32x4){0.f, 0.f, 0.f, 0.f};

  int aoff[2], boff[6];
  #pragma unroll
  for (int m = 0; m < 2; ++m) {
    int row = wm * 32 + m * 16 + l15;
    aoff[m] = row * 64 + ((qw ^ (row & 3) ^ ((row & 4) >> 1)) << 4);
  }
  #pragma unroll
  for (int n = 0; n < 6; ++n) {
    int row = wn * 96 + n * 16 + l15;
    boff[n] = row * 64 + ((qw ^ (row & 3) ^ ((row & 4) >> 1)) << 4);
  }

  // K-loop: 24 phases, counted vmcnt, 2 raw barriers per phase
  for (int k = 0; k < 24; ++k) {
    const char* cA = smem + (k & 1) * 4096;
    const char* cB = smem + 8192 + (k & 1) * 24576;
    char* nA = (char*)smem + ((k + 1) & 1) * 4096;
    char* nB = (char*)smem + 8192 + ((k + 1) & 1) * 24576;
    if (k < 23) {
      #pragma unroll
      for (int it = 0; it < 3; ++it)
        gload16(ewb_t + b_src[it] + (k + 1) * 32, nB + b_dst[it]);
      if (tid < 256) gload16(tokb + a_src + (k + 1) * 32, nA + a_dst);
      if (wid < 4) VM(4); else VM(3);
    } else {
      VM(0);
    }
    __builtin_amdgcn_s_barrier();
    __builtin_amdgcn_sched_barrier(0);
    short8 af[2], bfv[6];
    #pragma unroll
    for (int m = 0; m < 2; ++m) af[m] = *(const short8*)(cA + aoff[m]);
    #pragma unroll
    for (int n = 0; n < 6; ++n) bfv[n] = *(const short8*)(cB + boff[n]);
    __builtin_amdgcn_s_setprio(1);
    #pragma unroll
    for (int m = 0; m < 2; ++m)
      #pragma unroll
      for (int n = 0; n < 6; ++n)
        acc[m][n] = __builtin_amdgcn_mfma_f32_16x16x32_bf16(af[m], bfv[n], acc[m][n], 0, 0, 0);
    __builtin_amdgcn_s_setprio(0);
    __builtin_amdgcn_sched_barrier(0);
    __builtin_amdgcn_s_barrier();
  }

  // issue fwb chunk 0 into HI buffer (in flight during h/combine)
  #pragma unroll
  for (int it = 0; it < 2; ++it) {
    int F = it * 512 + tid, r = F >> 3, s = F & 7;
    gload16(fwb + (size_t)r * HID + ((s ^ (r & 7)) << 3),
            smem + 58368 + (it * 512 + wid * 64) * 16);
  }

  // h -> LDS bf16 [64][392]
  unsigned short* hl = (unsigned short*)(smem + 8192);
  #pragma unroll
  for (int m = 0; m < 2; ++m)
    #pragma unroll
    for (int n = 0; n < 6; ++n)
      #pragma unroll
      for (int i = 0; i < 4; ++i) {
        int row = wm * 32 + m * 16 + qw * 4 + i;
        int col = wn * 96 + n * 16 + l15;
        hl[row * 392 + col] = f2bf(acc[m][n][i]);
      }
  LGKM0;
  __builtin_amdgcn_s_barrier();

  // gated combine -> y bf16 (swizzled) at smem[0,8192)
  {
    int t = tid >> 3, j0 = (tid & 7) * 8;
    float4 rr = rec[t0 + t];
    int e0 = (int)rr.x, e1 = (int)rr.y;
    float g0 = rr.z, g1 = rr.w;
    short8 h0 = *(const short8*)(hl + t * 392 + e0 * 64 + j0);
    short8 h1 = *(const short8*)(hl + t * 392 + e1 * 64 + j0);
    const float4* ep0 = (const float4*)(eb + e0 * 64 + j0);
    const float4* ep1 = (const float4*)(eb + e1 * 64 + j0);
    float4 b0a = ep0[0], b0b = ep0[1], b1a = ep1[0], b1b = ep1[1];
    float be0[8] = {b0a.x, b0a.y, b0a.z, b0a.w, b0b.x, b0b.y, b0b.z, b0b.w};
    float be1[8] = {b1a.x, b1a.y, b1a.z, b1a.w, b1b.x, b1b.y, b1b.z, b1b.w};
    short8 ov;
    #pragma unroll
    for (int j = 0; j < 8; ++j) {
      float v = g0 * (b2f((unsigned short)h0[j]) + be0[j])
              + g1 * (b2f((unsigned short)h1[j]) + be1[j]);
      ov[j] = (short)f2bf(v);
    }
    *(short8*)(smem + t * 128 + ((((tid & 7)) ^ (t & 7)) << 4)) = ov;
  }
  LGKM0;
  __builtin_amdgcn_s_barrier();

  // FFN: 6 chunks of 128 cols, fwb dbuf HI/LO, counted vmcnt
  for (int c = 0; c < 6; ++c) {
    const char* cF = smem + ((c & 1) ? 8192 : 58368);
    char* nF = (char*)smem + ((c & 1) ? 58368 : 8192);
    if (c < 5) {
      #pragma unroll
      for (int it = 0; it < 2; ++it) {
        int F = it * 512 + tid, r = F >> 3, s = F & 7;
        gload16(fwb + (size_t)((c + 1) * 128 + r) * HID + ((s ^ (r & 7)) << 3),
                nF + (it * 512 + wid * 64) * 16);
      }
      VM(2);
    } else {
      VM(0);
    }
    __builtin_amdgcn_s_barrier();
    __builtin_amdgcn_sched_barrier(0);
    f32x4 a2[2][2];
    #pragma unroll
    for (int m = 0; m < 2; ++m)
      #pragma unroll
      for (int n = 0; n < 2; ++n) a2[m][n] = (f32x4){0.f, 0.f, 0.f, 0.f};
    #pragma unroll
    for (int kk = 0; kk < 2; ++kk) {
      short8 ay[2], bw[2];
      #pragma unroll
      for (int m = 0; m < 2; ++m) {
        int row = wm * 32 + m * 16 + l15;
        ay[m] = *(const short8*)(smem + row * 128 + (((kk * 4 + qw) ^ (row & 7)) << 4));
      }
      #pragma unroll
      for (int n = 0; n < 2; ++n) {
        int rw = wn * 32 + n * 16 + l15;
        bw[n] = *(const short8*)(cF + rw * 128 + (((kk * 4 + qw) ^ (rw & 7)) << 4));
      }
      __builtin_amdgcn_s_setprio(1);
      #pragma unroll
      for (int m = 0; m < 2; ++m)
        #pragma unroll
        for (int n = 0; n < 2; ++n)
          a2[m][n] = __builtin_amdgcn_mfma_f32_16x16x32_bf16(ay[m], bw[n], a2[m][n], 0, 0, 0);
      __builtin_amdgcn_s_setprio(0);
    }
    #pragma unroll
    for (int n = 0; n < 2; ++n) {
      int col = c * 128 + wn * 32 + n * 16 + l15;
      float bias = fb[col];
      #pragma unroll
      for (int m = 0; m < 2; ++m)
        #pragma unroll
        for (int i = 0; i < 4; ++i) {
          int rl = wm * 32 + m * 16 + qw * 4 + i;
          out[(size_t)rb[rl] + col] = a2[m][n][i] + bias;
        }
    }
    __builtin_amdgcn_sched_barrier(0);
    __builtin_amdgcn_s_barrier();
  }
}

}  // namespace

extern "C" void kernel_launch(void* const* d_in, const int* in_sizes, int n_in,
                              void* d_out, int out_size, void* d_ws, size_t ws_size,
                              hipStream_t stream)
{
  const float* x  = (const float*)d_in[0];
  const float* xi = (const float*)d_in[1];
  const float* wg = (const float*)d_in[2];
  const float* ew = (const float*)d_in[3];
  const float* eb = (const float*)d_in[4];
  const float* fw = (const float*)d_in[5];
  const float* fb = (const float*)d_in[6];
  float* out = (float*)d_out;

  char* w = (char*)d_ws;
  float4*         rec   = (float4*)w;                              // 327,680 B
  unsigned short* ewb_t = (unsigned short*)(w + 327680);           // 589,824 B
  unsigned short* fwb   = (unsigned short*)(w + 327680 + 589824);  //  98,304 B

  // gate: 2560 blocks x 8 tokens; +84 weight-prep blocks
  pre_kernel<<<84 + 2560, 256, 0, stream>>>(x, xi, wg, ew, fw, out, rec, ewb_t, fwb);
  moe_kernel<<<321, 512, 0, stream>>>(ewb_t, eb, fwb, fb, rec, out);
}